// Round 15
// baseline (356.931 us; speedup 1.0000x reference)
//
#include <hip/hip_runtime.h>
#include <hip/hip_bf16.h>
#include <hip/hip_cooperative_groups.h>

namespace cg = cooperative_groups;

#define N_NODES 50000
#define N_EDGES 800000
#define NCHUNK 256        // edge chunks
#define EPC 3125          // edges per chunk (= N_EDGES/NCHUNK exactly)
#define NBUCKET 196       // coarse buckets: dst>>8 (50000/256 -> 196)

typedef __attribute__((ext_vector_type(8))) short bf16x8;
typedef __attribute__((ext_vector_type(4))) float f32x4;
typedef __attribute__((ext_vector_type(2))) float f32x2;
typedef unsigned short ushort_t;

__device__ __forceinline__ float bf2f(unsigned short u) {
    union { unsigned u32; float f; } v; v.u32 = (unsigned)u << 16; return v.f;
}
__device__ __forceinline__ unsigned short f2bf(float f) {
    __hip_bfloat16 h = __float2bfloat16(f);
    return *reinterpret_cast<unsigned short*>(&h);
}
__device__ __forceinline__ f32x2 bfpair(unsigned u) {
    union { unsigned a; float f; } lo, hi;
    lo.a = u << 16;
    hi.a = u & 0xFFFF0000u;
    f32x2 r; r.x = lo.f; r.y = hi.f; return r;
}
// d += a * b (packed f32x2; all operands are VGPR pairs — VOP3P requirement)
__device__ __forceinline__ void pkfma(f32x2& d, f32x2 a, f32x2 b) {
    asm("v_pk_fma_f32 %0, %1, %2, %0" : "+v"(d) : "v"(a), "v"(b));
}
__device__ __forceinline__ void gload16(const void* src, void* lds) {
    __builtin_amdgcn_global_load_lds(
        (const __attribute__((address_space(1))) unsigned int*)src,
        (__attribute__((address_space(3))) unsigned int*)lds, 16, 0, 0);
}

// inline int64-vs-int32 layout detection (odd 32-bit words all zero -> int64)
__device__ __forceinline__ int detect_is32_block(const unsigned* __restrict__ w,
                                                 int* s_is32, int tid) {
    if (tid == 0) {
        unsigned o = 0;
#pragma unroll
        for (int k = 1; k < 32; k += 2) o |= w[k];
        *s_is32 = (o != 0u);
    }
    __syncthreads();
    return *s_is32;
}

__device__ __forceinline__ int edge_elem(const unsigned* __restrict__ w, int is32, long long idx) {
    return is32 ? (int)w[idx] : (int)w[2 * idx];
}

// ---------------- fused prep: x->bf16, W1^T, W2^T ----------------
#define CONV_BLOCKS 6250   /* 50000*128/4 / 256 */
#define PREP_W_BLOCKS (CONV_BLOCKS + 128 + 256)
__global__ void __launch_bounds__(256) prep_kernel(const float* __restrict__ x,
                                                   ushort_t* __restrict__ xbf,
                                                   const float* __restrict__ W1,
                                                   ushort_t* __restrict__ W1t,
                                                   const float* __restrict__ W2,
                                                   ushort_t* __restrict__ W2t) {
    int b = blockIdx.x, t = threadIdx.x;
    if (b < CONV_BLOCKS) {
        int i = b * 256 + t;
        float4 v = ((const float4*)x)[i];
        ushort4 o;
        o.x = f2bf(v.x); o.y = f2bf(v.y); o.z = f2bf(v.z); o.w = f2bf(v.w);
        ((ushort4*)xbf)[i] = o;
    } else if (b < CONV_BLOCKS + 128) {
        int id = (b - CONV_BLOCKS) * 256 + t;       // id = n*128 + k
        int n = id >> 7, k = id & 127;
        W1t[id] = f2bf(W1[k * 256 + n]);
    } else {
        int id = (b - CONV_BLOCKS - 128) * 256 + t; // id = n*256 + k
        int n = id >> 8, k = id & 255;
        W2t[id] = f2bf(W2[k * 256 + n]);
    }
}

// ---------------- cooperative CSR build: hist -> scan -> scatter -> sort -> perm ----------------
__global__ void __launch_bounds__(256) csr_build_kernel(
    const unsigned* __restrict__ ew, int* __restrict__ chunkHist,
    int* __restrict__ chunkOff, int* __restrict__ bsum, int* __restrict__ boff,
    unsigned* __restrict__ ebuf, unsigned* __restrict__ edge_csr,
    int* __restrict__ row_ptr, int* __restrict__ dhist, int* __restrict__ dcur,
    int* __restrict__ perm) {
    cg::grid_group grid = cg::this_grid();
    int b = blockIdx.x, t = threadIdx.x;
    __shared__ int s_is32;
    __shared__ int sh[256];
    __shared__ int sh2[256];
    __shared__ int d64a[64], d64b[64], d64c[64];

    int is32 = detect_is32_block(ew, &s_is32, t);

    // ---- phase 1: per-chunk coarse histogram (all 256 blocks); zero dhist/dcur ----
    if (b == 0 && t < 64) { dhist[t] = 0; dcur[t] = 0; }
    for (int k = t; k < NBUCKET; k += 256) sh[k] = 0;
    __syncthreads();
    {
        long long e0 = (long long)b * EPC;
        for (int k = t; k < EPC; k += 256) {
            int d = edge_elem(ew, is32, (long long)N_EDGES + e0 + k);
            atomicAdd(&sh[d >> 8], 1);
        }
    }
    __syncthreads();
    for (int k = t; k < NBUCKET; k += 256) chunkHist[k * NCHUNK + b] = sh[k];
    grid.sync();

    // ---- phase 2: per-bucket-row exclusive scan (blocks 0..195) ----
    if (b < NBUCKET) {
        int i = b * 256 + t;
        int v = chunkHist[i];
        sh[t] = v;
        __syncthreads();
        for (int off = 1; off < 256; off <<= 1) {
            int y = (t >= off) ? sh[t - off] : 0;
            __syncthreads();
            sh[t] += y;
            __syncthreads();
        }
        chunkOff[i] = sh[t] - v;
        if (t == 255) bsum[b] = sh[255];
    }
    grid.sync();

    // ---- phase 3: block 0 scans bsum[196] -> boff ----
    if (b == 0) {
        int v = (t < NBUCKET) ? bsum[t] : 0;
        sh[t] = v;
        __syncthreads();
        for (int off = 1; off < 256; off <<= 1) {
            int y = (t >= off) ? sh[t - off] : 0;
            __syncthreads();
            sh[t] += y;
            __syncthreads();
        }
        if (t < NBUCKET) boff[t] = sh[t] - v;
    }
    grid.sync();

    // ---- phase 4: add bucket-row base offsets ----
    if (b < NBUCKET) chunkOff[b * 256 + t] += boff[b];
    grid.sync();

    // ---- phase 5: scatter edges into bucket-sorted runs (all 256 blocks) ----
    for (int k = t; k < NBUCKET; k += 256) sh[k] = chunkOff[k * NCHUNK + b];
    __syncthreads();
    {
        long long e0 = (long long)b * EPC;
        for (int k = t; k < EPC; k += 256) {
            long long e = e0 + k;
            unsigned s = (unsigned)edge_elem(ew, is32, e);
            int d = edge_elem(ew, is32, (long long)N_EDGES + e);
            int pos = atomicAdd(&sh[d >> 8], 1);
            ebuf[pos] = s | ((unsigned)d << 16);
        }
    }
    grid.sync();

    // ---- phase 6: exact per-dst sort within bucket + row_ptr + degree hist ----
    if (b < NBUCKET) {
        int start = chunkOff[b * NCHUNK];
        int end = (b + 1 < NBUCKET) ? chunkOff[(b + 1) * NCHUNK] : N_EDGES;
        sh[t] = 0;
        if (t < 64) d64a[t] = 0;
        __syncthreads();
        for (int e = start + t; e < end; e += 256)
            atomicAdd(&sh[(int)(ebuf[e] >> 16) & 255], 1);
        __syncthreads();
        int node = b * 256 + t;
        int mydeg = sh[t];
        if (node < N_NODES) atomicAdd(&d64a[mydeg < 63 ? mydeg : 63], 1);
        sh2[t] = mydeg;
        __syncthreads();
        for (int off = 1; off < 256; off <<= 1) {
            int y = (t >= off) ? sh2[t - off] : 0;
            __syncthreads();
            sh2[t] += y;
            __syncthreads();
        }
        int excl = sh2[t] - mydeg;
        if (node <= N_NODES) row_ptr[node] = start + excl;  // node==N_NODES at b=195,t=80
        sh[t] = start + excl;  // becomes cursor
        __syncthreads();
        for (int e = start + t; e < end; e += 256) {
            unsigned pk = ebuf[e];
            int pos = atomicAdd(&sh[(pk >> 16) & 255], 1);
            edge_csr[pos] = pk;
        }
        if (t < 64 && d64a[t]) atomicAdd(&dhist[t], d64a[t]);
    }
    grid.sync();

    // ---- phase 7: degree-grouped perm scatter (blocks 0..195, inlined bin scan) ----
    if (b < NBUCKET) {
        int i = b * 256 + t;
        if (t < 64) {
            int v = dhist[t];
            int sum = v;
#pragma unroll
            for (int off = 1; off < 64; off <<= 1) {
                int y = __shfl_up(sum, off, 64);
                if (t >= off) sum += y;
            }
            d64b[t] = sum - v;   // sbase
            d64a[t] = 0;         // lh
        }
        __syncthreads();
        int deg = 0;
        if (i < N_NODES) {
            deg = row_ptr[i + 1] - row_ptr[i];
            if (deg > 63) deg = 63;
            atomicAdd(&d64a[deg], 1);
        }
        __syncthreads();
        if (t < 64) {
            d64c[t] = d64a[t] ? (d64b[t] + atomicAdd(&dcur[t], d64a[t])) : 0;  // lbase
            d64a[t] = 0;
        }
        __syncthreads();
        if (i < N_NODES) {
            int rank = atomicAdd(&d64a[deg], 1);
            perm[d64c[deg] + rank] = i;
        }
    }
}

// ---------------- MFMA bf16 GEMM + fused alpha logits ----------------
// C[M,256] = A[M,K](bf16) @ Wt^T, stored as fp8 e4m3 (1B/ch).
// colblock == head; epilogue computes alpha_s/alpha_d from fp32 accs.
template <int K>
__global__ void __launch_bounds__(256) mfma_gemm_kernel(const ushort_t* __restrict__ A,
                                                        const ushort_t* __restrict__ Wt,
                                                        void* __restrict__ Cv, int M,
                                                        const float* __restrict__ a_src,
                                                        const float* __restrict__ a_dst,
                                                        float* __restrict__ alpha_s,
                                                        float* __restrict__ alpha_d) {
    constexpr int CPR = K / 8;
    constexpr int NT = K / 64;
    __shared__ ushort_t Bs[64 * K];
    __shared__ ushort_t As[2][64 * 64];
    __shared__ float ps[64][2], pd[64][2];

    int tid = threadIdx.x;
    int wave = tid >> 6, lane = tid & 63;
    int l15 = lane & 15, l4 = lane >> 4;
    int wr = wave >> 1, wc = wave & 1;
    int colblock = blockIdx.x;   // head
    int rowblock = blockIdx.y;

    for (int base = 0; base < 64 * CPR; base += 256) {
        int p = base + wave * 64 + lane;
        int row = p / CPR;
        int cs = p % CPR;
        int c = cs ^ (row & 7);
        const ushort_t* src = Wt + (long long)(colblock * 64 + row) * K + c * 8;
        void* dst = ((char*)Bs) + (base + wave * 64) * 16;
        gload16(src, dst);
    }
    {
        int r = lane >> 3, cs = lane & 7;
        int c = cs ^ r;
#pragma unroll
        for (int q = 0; q < 2; ++q) {
            int lrow = wave * 16 + q * 8;
            int grow = rowblock * 64 + lrow + r;
            if (grow >= M) grow = M - 1;
            const ushort_t* src = A + (long long)grow * K + c * 8;
            void* dst = ((char*)&As[0][0]) + lrow * 128;
            gload16(src, dst);
        }
    }
    __syncthreads();

    f32x4 acc[2][2] = {};
#pragma unroll
    for (int t = 0; t < NT; ++t) {
        if (t + 1 < NT) {
            int r = lane >> 3, cs = lane & 7;
            int c = cs ^ r;
#pragma unroll
            for (int q = 0; q < 2; ++q) {
                int lrow = wave * 16 + q * 8;
                int grow = rowblock * 64 + lrow + r;
                if (grow >= M) grow = M - 1;
                const ushort_t* src = A + (long long)grow * K + (t + 1) * 64 + c * 8;
                void* dst = ((char*)&As[(t + 1) & 1][0]) + lrow * 128;
                gload16(src, dst);
            }
        }
        const ushort_t* At = &As[t & 1][0];
#pragma unroll
        for (int w = 0; w < 2; ++w) {
            bf16x8 a[2], b[2];
#pragma unroll
            for (int mi = 0; mi < 2; ++mi) {
                int row = wr * 32 + mi * 16 + l15;
                int slot = (w * 4 + l4) ^ (l15 & 7);
                a[mi] = *(const bf16x8*)&At[row * 64 + slot * 8];
            }
#pragma unroll
            for (int ni = 0; ni < 2; ++ni) {
                int brow = wc * 32 + ni * 16 + l15;
                int slot = (t * 8 + w * 4 + l4) ^ (l15 & 7);
                b[ni] = *(const bf16x8*)&Bs[brow * CPR * 8 + slot * 8];
            }
#pragma unroll
            for (int mi = 0; mi < 2; ++mi)
#pragma unroll
                for (int ni = 0; ni < 2; ++ni)
                    acc[mi][ni] = __builtin_amdgcn_mfma_f32_16x16x32_bf16(a[mi], b[ni],
                                                                          acc[mi][ni], 0, 0, 0);
        }
        __syncthreads();
    }

    // ---- fused alpha partials: per-row dot with a_src/a_dst (this head) ----
    {
        float as0 = a_src[colblock * 64 + wc * 32 + l15];
        float as1 = a_src[colblock * 64 + wc * 32 + 16 + l15];
        float ad0 = a_dst[colblock * 64 + wc * 32 + l15];
        float ad1 = a_dst[colblock * 64 + wc * 32 + 16 + l15];
#pragma unroll
        for (int mi = 0; mi < 2; ++mi)
#pragma unroll
            for (int q = 0; q < 4; ++q) {
                float sv = acc[mi][0][q] * as0 + acc[mi][1][q] * as1;
                float dv = acc[mi][0][q] * ad0 + acc[mi][1][q] * ad1;
#pragma unroll
                for (int w = 1; w < 16; w <<= 1) {
                    sv += __shfl_xor(sv, w, 64);
                    dv += __shfl_xor(dv, w, 64);
                }
                if (l15 == 0) {
                    int row = wr * 32 + mi * 16 + l4 * 4 + q;
                    ps[row][wc] = sv;
                    pd[row][wc] = dv;
                }
            }
    }

    // ---- epilogue: repack via LDS (bf16 staging), store fp8 ----
    ushort_t* ep = ((ushort_t*)&As[0][0]) + wave * 1280;
#pragma unroll
    for (int mi = 0; mi < 2; ++mi)
#pragma unroll
        for (int ni = 0; ni < 2; ++ni)
#pragma unroll
            for (int q = 0; q < 4; ++q) {
                int row = mi * 16 + l4 * 4 + q;
                int col = ni * 16 + l15;
                ep[row * 40 + col] = f2bf(acc[mi][ni][q]);
            }
    __syncthreads();
#pragma unroll
    for (int j = 0; j < 2; ++j) {
        int p = lane * 2 + j;
        int row = p >> 2, seg = p & 3;
        uint4 v = *(const uint4*)&ep[row * 40 + seg * 8];
        int grow = rowblock * 64 + wr * 32 + row;
        int gcol = colblock * 64 + wc * 32 + seg * 8;
        if (grow < M) {
            f32x2 f01 = bfpair(v.x), f23 = bfpair(v.y);
            f32x2 f45 = bfpair(v.z), f67 = bfpair(v.w);
            int d0 = 0, d1 = 0;
            d0 = __builtin_amdgcn_cvt_pk_fp8_f32(f01.x, f01.y, d0, false);
            d0 = __builtin_amdgcn_cvt_pk_fp8_f32(f23.x, f23.y, d0, true);
            d1 = __builtin_amdgcn_cvt_pk_fp8_f32(f45.x, f45.y, d1, false);
            d1 = __builtin_amdgcn_cvt_pk_fp8_f32(f67.x, f67.y, d1, true);
            uint2 o; o.x = (unsigned)d0; o.y = (unsigned)d1;
            *(uint2*)((char*)Cv + (long long)grow * 256 + gcol) = o;
        }
    }
    if (tid < 64) {
        int ga = rowblock * 64 + tid;
        if (ga < M) {
            alpha_s[ga * 4 + colblock] = ps[tid][0] + ps[tid][1];
            alpha_d[ga * 4 + colblock] = pd[tid][0] + pd[tid][1];
        }
    }
}

// ---------------- softmax-weighted aggregation (one wave per node, degree-grouped) ----------------
// Per-edge weight exp deduplicated across the 16-lane head group:
// lane l computes wt for edge (l15 & (U-1)), head (l>>4); redistribution via __shfl.
template <int U>
__device__ __forceinline__ void agg_batch(int p, const unsigned* __restrict__ edge_csr,
                                          const float* __restrict__ alpha_s,
                                          const char* __restrict__ gb, unsigned loff,
                                          int l15, int hd, float ad, float& wsum,
                                          f32x2& acc01, f32x2& acc23) {
    int j[U]; unsigned hh[U];
#pragma unroll
    for (int u = 0; u < U; ++u) j[u] = (int)(edge_csr[p + u] & 0xFFFFu);
#pragma unroll
    for (int u = 0; u < U; ++u)
        hh[u] = *(const unsigned*)(gb + (((unsigned)j[u] << 8) | loff));
    // one exp per lane (direct load avoids runtime-indexed register array -> scratch)
    int myj = (int)(edge_csr[p + (l15 & (U - 1))] & 0xFFFFu);
    float e = alpha_s[myj * 4 + hd] + ad;
    e = e > 0.f ? e : 0.2f * e;
    float wt_mine = __expf(e);
    int sbase = hd << 4;
#pragma unroll
    for (int u = 0; u < U; ++u) {
        float wt = __shfl(wt_mine, sbase | u, 64);
        wsum += wt;
        f32x2 wp; wp.x = wt; wp.y = wt;
        pkfma(acc01, wp, __builtin_amdgcn_cvt_pk_f32_fp8(hh[u], false));
        pkfma(acc23, wp, __builtin_amdgcn_cvt_pk_f32_fp8(hh[u], true));
    }
}

template <int LAYER>
__global__ void __launch_bounds__(256) aggregate_kernel(
    const void* __restrict__ gv, const float* __restrict__ alpha_s,
    const float* __restrict__ alpha_d, const int* __restrict__ row_ptr,
    const unsigned* __restrict__ edge_csr, const int* __restrict__ perm,
    const float* __restrict__ bias, ushort_t* __restrict__ out_bf,
    const float* __restrict__ fc_w, const float* __restrict__ fc_b,
    float* __restrict__ final_out) {
    int wave = threadIdx.x >> 6;
    int lane = threadIdx.x & 63;
    int i = __builtin_amdgcn_readfirstlane(perm[blockIdx.x * 4 + wave]);
    int hd = lane >> 4;
    int l15 = lane & 15;
    const char* gb = (const char*)gv;           // fp8 rows: 256 B/row
    unsigned loff = (unsigned)(lane << 2);

    float ad = alpha_d[i * 4 + hd];
    // self loop
    float e0 = alpha_s[i * 4 + hd] + ad;
    e0 = e0 > 0.f ? e0 : 0.2f * e0;
    float w0 = __expf(e0);
    f32x2 acc01 = {0.f, 0.f}, acc23 = {0.f, 0.f};
    {
        unsigned sv = *(const unsigned*)(gb + (((unsigned)i << 8) | loff));
        f32x2 wp0; wp0.x = w0; wp0.y = w0;
        pkfma(acc01, wp0, __builtin_amdgcn_cvt_pk_f32_fp8(sv, false));
        pkfma(acc23, wp0, __builtin_amdgcn_cvt_pk_f32_fp8(sv, true));
    }
    float wsum = w0;

    int p = __builtin_amdgcn_readfirstlane(row_ptr[i]);
    int p1 = __builtin_amdgcn_readfirstlane(row_ptr[i + 1]);
    for (; p + 16 <= p1; p += 16)
        agg_batch<16>(p, edge_csr, alpha_s, gb, loff, l15, hd, ad, wsum, acc01, acc23);
    for (; p + 8 <= p1; p += 8)
        agg_batch<8>(p, edge_csr, alpha_s, gb, loff, l15, hd, ad, wsum, acc01, acc23);
    for (; p + 4 <= p1; p += 4)
        agg_batch<4>(p, edge_csr, alpha_s, gb, loff, l15, hd, ad, wsum, acc01, acc23);
    for (; p < p1; ++p)
        agg_batch<1>(p, edge_csr, alpha_s, gb, loff, l15, hd, ad, wsum, acc01, acc23);

    float inv = 1.f / (wsum + 1e-16f);
    int c = lane * 4;
    float4 b4 = *(const float4*)&bias[c];
    float o0 = acc01.x * inv + b4.x;
    float o1 = acc01.y * inv + b4.y;
    float o2 = acc23.x * inv + b4.z;
    float o3 = acc23.y * inv + b4.w;
    o0 = o0 > 0.f ? o0 : __expf(o0) - 1.f;
    o1 = o1 > 0.f ? o1 : __expf(o1) - 1.f;
    o2 = o2 > 0.f ? o2 : __expf(o2) - 1.f;
    o3 = o3 > 0.f ? o3 : __expf(o3) - 1.f;
    if (LAYER == 1) {
        ushort4 o;
        o.x = f2bf(o0); o.y = f2bf(o1); o.z = f2bf(o2); o.w = f2bf(o3);
        ((ushort4*)out_bf)[(long long)i * 64 + lane] = o;
    } else {
        float4 fw = *(const float4*)&fc_w[c];
        float dot = o0 * fw.x + o1 * fw.y + o2 * fw.z + o3 * fw.w;
#pragma unroll
        for (int off = 32; off; off >>= 1) dot += __shfl_down(dot, off, 64);
        if (lane == 0) final_out[i] = 1.f / (1.f + __expf(-(dot + fc_b[0])));
    }
}

// ---------------- launch ----------------
extern "C" void kernel_launch(void* const* d_in, const int* in_sizes, int n_in,
                              void* d_out, int out_size, void* d_ws, size_t ws_size,
                              hipStream_t stream) {
    const float* x   = (const float*)d_in[0];
    const unsigned* ei = (const unsigned*)d_in[1];
    const float* W1  = (const float*)d_in[2];
    const float* as1 = (const float*)d_in[3];
    const float* ad1 = (const float*)d_in[4];
    const float* b1  = (const float*)d_in[5];
    const float* W2  = (const float*)d_in[6];
    const float* as2 = (const float*)d_in[7];
    const float* ad2 = (const float*)d_in[8];
    const float* b2  = (const float*)d_in[9];
    const float* fcw = (const float*)d_in[10];
    const float* fcb = (const float*)d_in[11];

    char* ws = (char*)d_ws;
    void* g1f8         = (void*)(ws + 0);               // 12.8 MB (fp8)
    void* g2f8         = (void*)(ws + 12800000);        // 12.8 MB (fp8)
    ushort_t* hactbf   = (ushort_t*)(ws + 25600000);    // 25.6 MB
    ushort_t* xbf      = (ushort_t*)(ws + 51200000);    // 12.8 MB
    ushort_t* W1t      = (ushort_t*)(ws + 64000000);
    ushort_t* W2t      = (ushort_t*)(ws + 64100000);
    float* asv         = (float*)(ws + 64300000);
    float* adv         = (float*)(ws + 65100000);
    int* row_ptr       = (int*)(ws + 65900000);         // 50001 ints
    int* chunkHist     = (int*)(ws + 66110000);         // 50176 ints
    int* chunkOff      = (int*)(ws + 66320000);         // 50176 ints
    unsigned* ebuf     = (unsigned*)(ws + 66530000);    // 3.2 MB (bucket-sorted)
    unsigned* edge_csr = (unsigned*)(ws + 69730000);    // 3.2 MB (exact CSR)
    int* perm          = (int*)(ws + 72930000);         // 200 KB (degree-grouped order)
    int* bsum          = (int*)(ws + 73130000);         // 196 ints
    int* boff          = (int*)(ws + 73131024);         // 196 ints
    int* dhist         = (int*)(ws + 73132048);         // 64 ints
    int* dcur          = (int*)(ws + 73132304);         // 64 ints

    prep_kernel<<<PREP_W_BLOCKS, 256, 0, stream>>>(x, xbf, W1, W1t, W2, W2t);

    {
        void* cargs[] = {(void*)&ei, (void*)&chunkHist, (void*)&chunkOff, (void*)&bsum,
                         (void*)&boff, (void*)&ebuf, (void*)&edge_csr, (void*)&row_ptr,
                         (void*)&dhist, (void*)&dcur, (void*)&perm};
        hipLaunchCooperativeKernel((const void*)csr_build_kernel, dim3(NCHUNK), dim3(256),
                                   cargs, 0, stream);
    }

    // layer 1 (g stored fp8)
    mfma_gemm_kernel<128><<<dim3(4, (N_NODES + 63) / 64), 256, 0, stream>>>(
        xbf, W1t, g1f8, N_NODES, as1, ad1, asv, adv);
    aggregate_kernel<1><<<N_NODES / 4, 256, 0, stream>>>(g1f8, asv, adv, row_ptr, edge_csr, perm,
                                                         b1, hactbf, nullptr, nullptr, nullptr);
    // layer 2 (g stored fp8)
    mfma_gemm_kernel<256><<<dim3(4, (N_NODES + 63) / 64), 256, 0, stream>>>(
        hactbf, W2t, g2f8, N_NODES, as2, ad2, asv, adv);
    aggregate_kernel<2><<<N_NODES / 4, 256, 0, stream>>>(g2f8, asv, adv, row_ptr, edge_csr, perm,
                                                         b2, nullptr, fcw, fcb, (float*)d_out);
}

// Round 16
// 173.949 us; speedup vs baseline: 2.0519x; 2.0519x over previous
//
#include <hip/hip_runtime.h>
#include <hip/hip_bf16.h>

#define N_NODES 50000
#define N_EDGES 800000
#define NCHUNK 256        // edge chunks
#define EPC 3125          // edges per chunk (= N_EDGES/NCHUNK exactly)
#define NBUCKET 196       // coarse buckets: dst>>8 (50000/256 -> 196)
#define SCAN_BLOCKS 196

typedef __attribute__((ext_vector_type(8))) short bf16x8;
typedef __attribute__((ext_vector_type(4))) float f32x4;
typedef __attribute__((ext_vector_type(2))) float f32x2;
typedef unsigned short ushort_t;

__device__ __forceinline__ float bf2f(unsigned short u) {
    union { unsigned u32; float f; } v; v.u32 = (unsigned)u << 16; return v.f;
}
__device__ __forceinline__ unsigned short f2bf(float f) {
    __hip_bfloat16 h = __float2bfloat16(f);
    return *reinterpret_cast<unsigned short*>(&h);
}
__device__ __forceinline__ f32x2 bfpair(unsigned u) {
    union { unsigned a; float f; } lo, hi;
    lo.a = u << 16;
    hi.a = u & 0xFFFF0000u;
    f32x2 r; r.x = lo.f; r.y = hi.f; return r;
}
// d += a * b (packed f32x2; all operands are VGPR pairs — VOP3P requirement)
__device__ __forceinline__ void pkfma(f32x2& d, f32x2 a, f32x2 b) {
    asm("v_pk_fma_f32 %0, %1, %2, %0" : "+v"(d) : "v"(a), "v"(b));
}
__device__ __forceinline__ void gload16(const void* src, void* lds) {
    __builtin_amdgcn_global_load_lds(
        (const __attribute__((address_space(1))) unsigned int*)src,
        (__attribute__((address_space(3))) unsigned int*)lds, 16, 0, 0);
}

// inline int64-vs-int32 layout detection (odd 32-bit words all zero -> int64)
__device__ __forceinline__ int detect_is32_block(const unsigned* __restrict__ w,
                                                 int* s_is32, int tid) {
    if (tid == 0) {
        unsigned o = 0;
#pragma unroll
        for (int k = 1; k < 32; k += 2) o |= w[k];
        *s_is32 = (o != 0u);
    }
    __syncthreads();
    return *s_is32;
}

__device__ __forceinline__ int edge_elem(const unsigned* __restrict__ w, int is32, long long idx) {
    return is32 ? (int)w[idx] : (int)w[2 * idx];
}

// ---------------- fused prep: x->bf16, W1^T, W2^T, S1 bucket histogram, zero dhist/dcur ----------------
#define CONV_BLOCKS 6250   /* 50000*128/4 / 256 */
#define PREP_W_BLOCKS (CONV_BLOCKS + 128 + 256)
__global__ void __launch_bounds__(256) prep_kernel(const float* __restrict__ x,
                                                   ushort_t* __restrict__ xbf,
                                                   const float* __restrict__ W1,
                                                   ushort_t* __restrict__ W1t,
                                                   const float* __restrict__ W2,
                                                   ushort_t* __restrict__ W2t,
                                                   const unsigned* __restrict__ ew,
                                                   int* __restrict__ chunkHist,
                                                   int* __restrict__ dhist,
                                                   int* __restrict__ dcur) {
    int b = blockIdx.x, t = threadIdx.x;
    if (b < CONV_BLOCKS) {
        if (b == 0 && t < 64) { dhist[t] = 0; dcur[t] = 0; }
        int i = b * 256 + t;
        float4 v = ((const float4*)x)[i];
        ushort4 o;
        o.x = f2bf(v.x); o.y = f2bf(v.y); o.z = f2bf(v.z); o.w = f2bf(v.w);
        ((ushort4*)xbf)[i] = o;
    } else if (b < CONV_BLOCKS + 128) {
        int id = (b - CONV_BLOCKS) * 256 + t;       // id = n*128 + k
        int n = id >> 7, k = id & 127;
        W1t[id] = f2bf(W1[k * 256 + n]);
    } else if (b < CONV_BLOCKS + 128 + 256) {
        int id = (b - CONV_BLOCKS - 128) * 256 + t; // id = n*256 + k
        int n = id >> 8, k = id & 255;
        W2t[id] = f2bf(W2[k * 256 + n]);
    } else {
        // S1: per-chunk coarse-bucket histogram (bucket-major out)
        __shared__ int s_is32;
        __shared__ int hist[NBUCKET];
        int c = b - PREP_W_BLOCKS;
        int is32 = detect_is32_block(ew, &s_is32, t);
        for (int k = t; k < NBUCKET; k += 256) hist[k] = 0;
        __syncthreads();
        long long e0 = (long long)c * EPC;
        for (int k = t; k < EPC; k += 256) {
            int d = edge_elem(ew, is32, (long long)N_EDGES + e0 + k);
            atomicAdd(&hist[d >> 8], 1);
        }
        __syncthreads();
        for (int k = t; k < NBUCKET; k += 256)
            chunkHist[k * NCHUNK + c] = hist[k];
    }
}

// ---------------- scan1: per-bucket-row local exclusive scan + row totals ----------------
__global__ void __launch_bounds__(256) scan1_kernel(const int* __restrict__ in,
                                                    int* __restrict__ excl, int* __restrict__ bsum) {
    __shared__ int s[256];
    int b = blockIdx.x, t = threadIdx.x, i = b * 256 + t;
    int v = in[i];
    s[t] = v;
    __syncthreads();
    for (int off = 1; off < 256; off <<= 1) {
        int y = (t >= off) ? s[t - off] : 0;
        __syncthreads();
        s[t] += y;
        __syncthreads();
    }
    excl[i] = s[t] - v;
    if (t == 255) bsum[b] = s[255];
}

// ---------------- S3: scatter edges into bucket-sorted order (bsum scan inlined) ----------------
__global__ void __launch_bounds__(256) bucket_scatter_kernel(const unsigned* __restrict__ ew,
                                                             const int* __restrict__ chunkOff,
                                                             const int* __restrict__ bsum,
                                                             unsigned* __restrict__ ebuf) {
    __shared__ int s_is32;
    __shared__ int cur[NBUCKET];
    __shared__ int sc[256];
    __shared__ int ex[NBUCKET];
    int t = threadIdx.x, b = blockIdx.x;
    int is32 = detect_is32_block(ew, &s_is32, t);
    // in-block exclusive scan of bsum[196] -> global bucket bases
    int v = (t < NBUCKET) ? bsum[t] : 0;
    sc[t] = v;
    __syncthreads();
    for (int off = 1; off < 256; off <<= 1) {
        int y = (t >= off) ? sc[t - off] : 0;
        __syncthreads();
        sc[t] += y;
        __syncthreads();
    }
    if (t < NBUCKET) ex[t] = sc[t] - v;
    __syncthreads();
    for (int k = t; k < NBUCKET; k += 256) cur[k] = ex[k] + chunkOff[k * NCHUNK + b];
    __syncthreads();
    long long e0 = (long long)b * EPC;
    for (int k = t; k < EPC; k += 256) {
        long long e = e0 + k;
        unsigned s = (unsigned)edge_elem(ew, is32, e);
        int d = edge_elem(ew, is32, (long long)N_EDGES + e);
        int pos = atomicAdd(&cur[d >> 8], 1);
        ebuf[pos] = s | ((unsigned)d << 16);
    }
}

// ---------------- S4: exact per-dst sort within bucket + row_ptr + degree hist ----------------
__global__ void __launch_bounds__(256) bucket_sort_kernel(const unsigned* __restrict__ ebuf,
                                                          const int* __restrict__ bsum,
                                                          unsigned* __restrict__ edge_csr,
                                                          int* __restrict__ row_ptr,
                                                          int* __restrict__ dhist) {
    __shared__ int cnt[256];
    __shared__ int s[256];
    __shared__ int dh[64];
    __shared__ int sstart, send;
    int b = blockIdx.x, t = threadIdx.x;
    // in-block exclusive scan of bsum -> start/end of this bucket
    int v = (t < NBUCKET) ? bsum[t] : 0;
    s[t] = v;
    __syncthreads();
    for (int off = 1; off < 256; off <<= 1) {
        int y = (t >= off) ? s[t - off] : 0;
        __syncthreads();
        s[t] += y;
        __syncthreads();
    }
    if (t == b) sstart = s[t] - v;
    if (b + 1 < NBUCKET) {
        if (t == b + 1) send = s[t] - v;
    } else {
        if (t == 0) send = N_EDGES;
    }
    __syncthreads();
    int start = sstart, end = send;
    cnt[t] = 0;
    if (t < 64) dh[t] = 0;
    __syncthreads();
    for (int e = start + t; e < end; e += 256) {
        int d = (int)(ebuf[e] >> 16);
        atomicAdd(&cnt[d & 255], 1);
    }
    __syncthreads();
    int node = b * 256 + t;
    int mydeg = cnt[t];
    if (node < N_NODES) atomicAdd(&dh[mydeg < 63 ? mydeg : 63], 1);
    s[t] = mydeg;
    __syncthreads();
    for (int off = 1; off < 256; off <<= 1) {
        int y = (t >= off) ? s[t - off] : 0;
        __syncthreads();
        s[t] += y;
        __syncthreads();
    }
    int excl = s[t] - mydeg;
    if (node <= N_NODES) row_ptr[node] = start + excl;  // node==N_NODES at b=195,t=80
    cnt[t] = start + excl;  // becomes cursor
    __syncthreads();
    for (int e = start + t; e < end; e += 256) {
        unsigned pk = ebuf[e];
        int pos = atomicAdd(&cnt[(pk >> 16) & 255], 1);
        edge_csr[pos] = pk;
    }
    if (t < 64 && dh[t]) atomicAdd(&dhist[t], dh[t]);
}

// ---------------- scatter node ids into degree-grouped perm (inlined bin scan) ----------------
__global__ void __launch_bounds__(256) dscatter_kernel(const int* __restrict__ row_ptr,
                                                       const int* __restrict__ dhist,
                                                       int* __restrict__ dcur,
                                                       int* __restrict__ perm) {
    __shared__ int lh[64], lbase[64], sbase[64];
    int t = threadIdx.x, i = blockIdx.x * 256 + t;
    if (t < 64) {
        int v = dhist[t];
        int sum = v;
#pragma unroll
        for (int off = 1; off < 64; off <<= 1) {
            int y = __shfl_up(sum, off, 64);
            if (t >= off) sum += y;
        }
        sbase[t] = sum - v;
        lh[t] = 0;
    }
    __syncthreads();
    int deg = 0;
    if (i < N_NODES) {
        deg = row_ptr[i + 1] - row_ptr[i];
        if (deg > 63) deg = 63;
        atomicAdd(&lh[deg], 1);
    }
    __syncthreads();
    if (t < 64) {
        lbase[t] = lh[t] ? (sbase[t] + atomicAdd(&dcur[t], lh[t])) : 0;
        lh[t] = 0;
    }
    __syncthreads();
    if (i < N_NODES) {
        int rank = atomicAdd(&lh[deg], 1);
        perm[lbase[deg] + rank] = i;
    }
}

// ---------------- MFMA bf16 GEMM + fused alpha logits ----------------
// C[M,256] = A[M,K](bf16) @ Wt^T, stored as fp8 e4m3 (1B/ch).
// colblock == head; epilogue computes alpha_s/alpha_d from fp32 accs.
template <int K>
__global__ void __launch_bounds__(256) mfma_gemm_kernel(const ushort_t* __restrict__ A,
                                                        const ushort_t* __restrict__ Wt,
                                                        void* __restrict__ Cv, int M,
                                                        const float* __restrict__ a_src,
                                                        const float* __restrict__ a_dst,
                                                        float* __restrict__ alpha_s,
                                                        float* __restrict__ alpha_d) {
    constexpr int CPR = K / 8;
    constexpr int NT = K / 64;
    __shared__ ushort_t Bs[64 * K];
    __shared__ ushort_t As[2][64 * 64];
    __shared__ float ps[64][2], pd[64][2];

    int tid = threadIdx.x;
    int wave = tid >> 6, lane = tid & 63;
    int l15 = lane & 15, l4 = lane >> 4;
    int wr = wave >> 1, wc = wave & 1;
    int colblock = blockIdx.x;   // head
    int rowblock = blockIdx.y;

    for (int base = 0; base < 64 * CPR; base += 256) {
        int p = base + wave * 64 + lane;
        int row = p / CPR;
        int cs = p % CPR;
        int c = cs ^ (row & 7);
        const ushort_t* src = Wt + (long long)(colblock * 64 + row) * K + c * 8;
        void* dst = ((char*)Bs) + (base + wave * 64) * 16;
        gload16(src, dst);
    }
    {
        int r = lane >> 3, cs = lane & 7;
        int c = cs ^ r;
#pragma unroll
        for (int q = 0; q < 2; ++q) {
            int lrow = wave * 16 + q * 8;
            int grow = rowblock * 64 + lrow + r;
            if (grow >= M) grow = M - 1;
            const ushort_t* src = A + (long long)grow * K + c * 8;
            void* dst = ((char*)&As[0][0]) + lrow * 128;
            gload16(src, dst);
        }
    }
    __syncthreads();

    f32x4 acc[2][2] = {};
#pragma unroll
    for (int t = 0; t < NT; ++t) {
        if (t + 1 < NT) {
            int r = lane >> 3, cs = lane & 7;
            int c = cs ^ r;
#pragma unroll
            for (int q = 0; q < 2; ++q) {
                int lrow = wave * 16 + q * 8;
                int grow = rowblock * 64 + lrow + r;
                if (grow >= M) grow = M - 1;
                const ushort_t* src = A + (long long)grow * K + (t + 1) * 64 + c * 8;
                void* dst = ((char*)&As[(t + 1) & 1][0]) + lrow * 128;
                gload16(src, dst);
            }
        }
        const ushort_t* At = &As[t & 1][0];
#pragma unroll
        for (int w = 0; w < 2; ++w) {
            bf16x8 a[2], b[2];
#pragma unroll
            for (int mi = 0; mi < 2; ++mi) {
                int row = wr * 32 + mi * 16 + l15;
                int slot = (w * 4 + l4) ^ (l15 & 7);
                a[mi] = *(const bf16x8*)&At[row * 64 + slot * 8];
            }
#pragma unroll
            for (int ni = 0; ni < 2; ++ni) {
                int brow = wc * 32 + ni * 16 + l15;
                int slot = (t * 8 + w * 4 + l4) ^ (l15 & 7);
                b[ni] = *(const bf16x8*)&Bs[brow * CPR * 8 + slot * 8];
            }
#pragma unroll
            for (int mi = 0; mi < 2; ++mi)
#pragma unroll
                for (int ni = 0; ni < 2; ++ni)
                    acc[mi][ni] = __builtin_amdgcn_mfma_f32_16x16x32_bf16(a[mi], b[ni],
                                                                          acc[mi][ni], 0, 0, 0);
        }
        __syncthreads();
    }

    // ---- fused alpha partials: per-row dot with a_src/a_dst (this head) ----
    {
        float as0 = a_src[colblock * 64 + wc * 32 + l15];
        float as1 = a_src[colblock * 64 + wc * 32 + 16 + l15];
        float ad0 = a_dst[colblock * 64 + wc * 32 + l15];
        float ad1 = a_dst[colblock * 64 + wc * 32 + 16 + l15];
#pragma unroll
        for (int mi = 0; mi < 2; ++mi)
#pragma unroll
            for (int q = 0; q < 4; ++q) {
                float sv = acc[mi][0][q] * as0 + acc[mi][1][q] * as1;
                float dv = acc[mi][0][q] * ad0 + acc[mi][1][q] * ad1;
#pragma unroll
                for (int w = 1; w < 16; w <<= 1) {
                    sv += __shfl_xor(sv, w, 64);
                    dv += __shfl_xor(dv, w, 64);
                }
                if (l15 == 0) {
                    int row = wr * 32 + mi * 16 + l4 * 4 + q;
                    ps[row][wc] = sv;
                    pd[row][wc] = dv;
                }
            }
    }

    // ---- epilogue: repack via LDS (bf16 staging), store fp8 ----
    ushort_t* ep = ((ushort_t*)&As[0][0]) + wave * 1280;
#pragma unroll
    for (int mi = 0; mi < 2; ++mi)
#pragma unroll
        for (int ni = 0; ni < 2; ++ni)
#pragma unroll
            for (int q = 0; q < 4; ++q) {
                int row = mi * 16 + l4 * 4 + q;
                int col = ni * 16 + l15;
                ep[row * 40 + col] = f2bf(acc[mi][ni][q]);
            }
    __syncthreads();
#pragma unroll
    for (int j = 0; j < 2; ++j) {
        int p = lane * 2 + j;
        int row = p >> 2, seg = p & 3;
        uint4 v = *(const uint4*)&ep[row * 40 + seg * 8];
        int grow = rowblock * 64 + wr * 32 + row;
        int gcol = colblock * 64 + wc * 32 + seg * 8;
        if (grow < M) {
            f32x2 f01 = bfpair(v.x), f23 = bfpair(v.y);
            f32x2 f45 = bfpair(v.z), f67 = bfpair(v.w);
            int d0 = 0, d1 = 0;
            d0 = __builtin_amdgcn_cvt_pk_fp8_f32(f01.x, f01.y, d0, false);
            d0 = __builtin_amdgcn_cvt_pk_fp8_f32(f23.x, f23.y, d0, true);
            d1 = __builtin_amdgcn_cvt_pk_fp8_f32(f45.x, f45.y, d1, false);
            d1 = __builtin_amdgcn_cvt_pk_fp8_f32(f67.x, f67.y, d1, true);
            uint2 o; o.x = (unsigned)d0; o.y = (unsigned)d1;
            *(uint2*)((char*)Cv + (long long)grow * 256 + gcol) = o;
        }
    }
    if (tid < 64) {
        int ga = rowblock * 64 + tid;
        if (ga < M) {
            alpha_s[ga * 4 + colblock] = ps[tid][0] + ps[tid][1];
            alpha_d[ga * 4 + colblock] = pd[tid][0] + pd[tid][1];
        }
    }
}

// ---------------- softmax-weighted aggregation (one wave per node, degree-grouped) ----------------
// Per-edge weight exp deduplicated across the 16-lane head group:
// lane l computes wt for edge (l15 & (U-1)), head (l>>4); redistribution via __shfl.
template <int U>
__device__ __forceinline__ void agg_batch(int p, const unsigned* __restrict__ edge_csr,
                                          const float* __restrict__ alpha_s,
                                          const char* __restrict__ gb, unsigned loff,
                                          int l15, int hd, float ad, float& wsum,
                                          f32x2& acc01, f32x2& acc23) {
    int j[U]; unsigned hh[U];
#pragma unroll
    for (int u = 0; u < U; ++u) j[u] = (int)(edge_csr[p + u] & 0xFFFFu);
#pragma unroll
    for (int u = 0; u < U; ++u)
        hh[u] = *(const unsigned*)(gb + (((unsigned)j[u] << 8) | loff));
    // one exp per lane (direct load avoids runtime-indexed register array -> scratch)
    int myj = (int)(edge_csr[p + (l15 & (U - 1))] & 0xFFFFu);
    float e = alpha_s[myj * 4 + hd] + ad;
    e = e > 0.f ? e : 0.2f * e;
    float wt_mine = __expf(e);
    int sbase = hd << 4;
#pragma unroll
    for (int u = 0; u < U; ++u) {
        float wt = __shfl(wt_mine, sbase | u, 64);
        wsum += wt;
        f32x2 wp; wp.x = wt; wp.y = wt;
        pkfma(acc01, wp, __builtin_amdgcn_cvt_pk_f32_fp8(hh[u], false));
        pkfma(acc23, wp, __builtin_amdgcn_cvt_pk_f32_fp8(hh[u], true));
    }
}

template <int LAYER>
__global__ void __launch_bounds__(256) aggregate_kernel(
    const void* __restrict__ gv, const float* __restrict__ alpha_s,
    const float* __restrict__ alpha_d, const int* __restrict__ row_ptr,
    const unsigned* __restrict__ edge_csr, const int* __restrict__ perm,
    const float* __restrict__ bias, ushort_t* __restrict__ out_bf,
    const float* __restrict__ fc_w, const float* __restrict__ fc_b,
    float* __restrict__ final_out) {
    int wave = threadIdx.x >> 6;
    int lane = threadIdx.x & 63;
    int i = __builtin_amdgcn_readfirstlane(perm[blockIdx.x * 4 + wave]);
    int hd = lane >> 4;
    int l15 = lane & 15;
    const char* gb = (const char*)gv;           // fp8 rows: 256 B/row
    unsigned loff = (unsigned)(lane << 2);

    float ad = alpha_d[i * 4 + hd];
    // self loop
    float e0 = alpha_s[i * 4 + hd] + ad;
    e0 = e0 > 0.f ? e0 : 0.2f * e0;
    float w0 = __expf(e0);
    f32x2 acc01 = {0.f, 0.f}, acc23 = {0.f, 0.f};
    {
        unsigned sv = *(const unsigned*)(gb + (((unsigned)i << 8) | loff));
        f32x2 wp0; wp0.x = w0; wp0.y = w0;
        pkfma(acc01, wp0, __builtin_amdgcn_cvt_pk_f32_fp8(sv, false));
        pkfma(acc23, wp0, __builtin_amdgcn_cvt_pk_f32_fp8(sv, true));
    }
    float wsum = w0;

    int p = __builtin_amdgcn_readfirstlane(row_ptr[i]);
    int p1 = __builtin_amdgcn_readfirstlane(row_ptr[i + 1]);
    for (; p + 16 <= p1; p += 16)
        agg_batch<16>(p, edge_csr, alpha_s, gb, loff, l15, hd, ad, wsum, acc01, acc23);
    for (; p + 8 <= p1; p += 8)
        agg_batch<8>(p, edge_csr, alpha_s, gb, loff, l15, hd, ad, wsum, acc01, acc23);
    for (; p + 4 <= p1; p += 4)
        agg_batch<4>(p, edge_csr, alpha_s, gb, loff, l15, hd, ad, wsum, acc01, acc23);
    for (; p < p1; ++p)
        agg_batch<1>(p, edge_csr, alpha_s, gb, loff, l15, hd, ad, wsum, acc01, acc23);

    float inv = 1.f / (wsum + 1e-16f);
    int c = lane * 4;
    float4 b4 = *(const float4*)&bias[c];
    float o0 = acc01.x * inv + b4.x;
    float o1 = acc01.y * inv + b4.y;
    float o2 = acc23.x * inv + b4.z;
    float o3 = acc23.y * inv + b4.w;
    o0 = o0 > 0.f ? o0 : __expf(o0) - 1.f;
    o1 = o1 > 0.f ? o1 : __expf(o1) - 1.f;
    o2 = o2 > 0.f ? o2 : __expf(o2) - 1.f;
    o3 = o3 > 0.f ? o3 : __expf(o3) - 1.f;
    if (LAYER == 1) {
        ushort4 o;
        o.x = f2bf(o0); o.y = f2bf(o1); o.z = f2bf(o2); o.w = f2bf(o3);
        ((ushort4*)out_bf)[(long long)i * 64 + lane] = o;
    } else {
        float4 fw = *(const float4*)&fc_w[c];
        float dot = o0 * fw.x + o1 * fw.y + o2 * fw.z + o3 * fw.w;
#pragma unroll
        for (int off = 32; off; off >>= 1) dot += __shfl_down(dot, off, 64);
        if (lane == 0) final_out[i] = 1.f / (1.f + __expf(-(dot + fc_b[0])));
    }
}

// ---------------- launch ----------------
extern "C" void kernel_launch(void* const* d_in, const int* in_sizes, int n_in,
                              void* d_out, int out_size, void* d_ws, size_t ws_size,
                              hipStream_t stream) {
    const float* x   = (const float*)d_in[0];
    const unsigned* ei = (const unsigned*)d_in[1];
    const float* W1  = (const float*)d_in[2];
    const float* as1 = (const float*)d_in[3];
    const float* ad1 = (const float*)d_in[4];
    const float* b1  = (const float*)d_in[5];
    const float* W2  = (const float*)d_in[6];
    const float* as2 = (const float*)d_in[7];
    const float* ad2 = (const float*)d_in[8];
    const float* b2  = (const float*)d_in[9];
    const float* fcw = (const float*)d_in[10];
    const float* fcb = (const float*)d_in[11];

    char* ws = (char*)d_ws;
    void* g1f8         = (void*)(ws + 0);               // 12.8 MB (fp8)
    void* g2f8         = (void*)(ws + 12800000);        // 12.8 MB (fp8)
    ushort_t* hactbf   = (ushort_t*)(ws + 25600000);    // 25.6 MB
    ushort_t* xbf      = (ushort_t*)(ws + 51200000);    // 12.8 MB
    ushort_t* W1t      = (ushort_t*)(ws + 64000000);
    ushort_t* W2t      = (ushort_t*)(ws + 64100000);
    float* asv         = (float*)(ws + 64300000);
    float* adv         = (float*)(ws + 65100000);
    int* row_ptr       = (int*)(ws + 65900000);         // 50001 ints
    int* chunkHist     = (int*)(ws + 66110000);         // 50176 ints
    int* chunkOff      = (int*)(ws + 66320000);         // 50176 ints (row-local prefixes)
    unsigned* ebuf     = (unsigned*)(ws + 66530000);    // 3.2 MB (bucket-sorted)
    unsigned* edge_csr = (unsigned*)(ws + 69730000);    // 3.2 MB (exact CSR)
    int* perm          = (int*)(ws + 72930000);         // 200 KB (degree-grouped order)
    int* bsum          = (int*)(ws + 73130000);         // 196 ints
    int* dhist         = (int*)(ws + 73132048);         // 64 ints
    int* dcur          = (int*)(ws + 73132304);         // 64 ints

    prep_kernel<<<PREP_W_BLOCKS + NCHUNK, 256, 0, stream>>>(x, xbf, W1, W1t, W2, W2t,
                                                            ei, chunkHist, dhist, dcur);
    scan1_kernel<<<SCAN_BLOCKS, 256, 0, stream>>>(chunkHist, chunkOff, bsum);
    bucket_scatter_kernel<<<NCHUNK, 256, 0, stream>>>(ei, chunkOff, bsum, ebuf);
    bucket_sort_kernel<<<NBUCKET, 256, 0, stream>>>(ebuf, bsum, edge_csr, row_ptr, dhist);
    dscatter_kernel<<<SCAN_BLOCKS, 256, 0, stream>>>(row_ptr, dhist, dcur, perm);

    // layer 1 (g stored fp8)
    mfma_gemm_kernel<128><<<dim3(4, (N_NODES + 63) / 64), 256, 0, stream>>>(
        xbf, W1t, g1f8, N_NODES, as1, ad1, asv, adv);
    aggregate_kernel<1><<<N_NODES / 4, 256, 0, stream>>>(g1f8, asv, adv, row_ptr, edge_csr, perm,
                                                         b1, hactbf, nullptr, nullptr, nullptr);
    // layer 2 (g stored fp8)
    mfma_gemm_kernel<256><<<dim3(4, (N_NODES + 63) / 64), 256, 0, stream>>>(
        hactbf, W2t, g2f8, N_NODES, as2, ad2, asv, adv);
    aggregate_kernel<2><<<N_NODES / 4, 256, 0, stream>>>(g2f8, asv, adv, row_ptr, edge_csr, perm,
                                                         b2, nullptr, fcw, fcb, (float*)d_out);
}

// Round 17
// 173.944 us; speedup vs baseline: 2.0520x; 1.0000x over previous
//
#include <hip/hip_runtime.h>
#include <hip/hip_bf16.h>

#define N_NODES 50000
#define N_EDGES 800000
#define NCHUNK 256        // edge chunks
#define EPC 3125          // edges per chunk (= N_EDGES/NCHUNK exactly)
#define NBUCKET 196       // coarse buckets: dst>>8 (50000/256 -> 196)
#define SCAN_BLOCKS 196

typedef __attribute__((ext_vector_type(8))) short bf16x8;
typedef __attribute__((ext_vector_type(4))) float f32x4;
typedef __attribute__((ext_vector_type(2))) float f32x2;
typedef unsigned short ushort_t;

__device__ __forceinline__ float bf2f(unsigned short u) {
    union { unsigned u32; float f; } v; v.u32 = (unsigned)u << 16; return v.f;
}
__device__ __forceinline__ unsigned short f2bf(float f) {
    __hip_bfloat16 h = __float2bfloat16(f);
    return *reinterpret_cast<unsigned short*>(&h);
}
__device__ __forceinline__ f32x2 bfpair(unsigned u) {
    union { unsigned a; float f; } lo, hi;
    lo.a = u << 16;
    hi.a = u & 0xFFFF0000u;
    f32x2 r; r.x = lo.f; r.y = hi.f; return r;
}
// d += a * b (packed f32x2; all operands are VGPR pairs — VOP3P requirement)
__device__ __forceinline__ void pkfma(f32x2& d, f32x2 a, f32x2 b) {
    asm("v_pk_fma_f32 %0, %1, %2, %0" : "+v"(d) : "v"(a), "v"(b));
}
__device__ __forceinline__ void gload16(const void* src, void* lds) {
    __builtin_amdgcn_global_load_lds(
        (const __attribute__((address_space(1))) unsigned int*)src,
        (__attribute__((address_space(3))) unsigned int*)lds, 16, 0, 0);
}

// inline int64-vs-int32 layout detection (odd 32-bit words all zero -> int64)
__device__ __forceinline__ int detect_is32_block(const unsigned* __restrict__ w,
                                                 int* s_is32, int tid) {
    if (tid == 0) {
        unsigned o = 0;
#pragma unroll
        for (int k = 1; k < 32; k += 2) o |= w[k];
        *s_is32 = (o != 0u);
    }
    __syncthreads();
    return *s_is32;
}

__device__ __forceinline__ int edge_elem(const unsigned* __restrict__ w, int is32, long long idx) {
    return is32 ? (int)w[idx] : (int)w[2 * idx];
}

// ---------------- fused prep: x->bf16, W1^T, W2^T, S1 bucket histogram, zero dhist/dcur ----------------
#define CONV_BLOCKS 6250   /* 50000*128/4 / 256 */
#define PREP_W_BLOCKS (CONV_BLOCKS + 128 + 256)
__global__ void __launch_bounds__(256) prep_kernel(const float* __restrict__ x,
                                                   ushort_t* __restrict__ xbf,
                                                   const float* __restrict__ W1,
                                                   ushort_t* __restrict__ W1t,
                                                   const float* __restrict__ W2,
                                                   ushort_t* __restrict__ W2t,
                                                   const unsigned* __restrict__ ew,
                                                   int* __restrict__ chunkHist,
                                                   int* __restrict__ dhist,
                                                   int* __restrict__ dcur) {
    int b = blockIdx.x, t = threadIdx.x;
    if (b < CONV_BLOCKS) {
        if (b == 0 && t < 64) { dhist[t] = 0; dcur[t] = 0; }
        int i = b * 256 + t;
        float4 v = ((const float4*)x)[i];
        ushort4 o;
        o.x = f2bf(v.x); o.y = f2bf(v.y); o.z = f2bf(v.z); o.w = f2bf(v.w);
        ((ushort4*)xbf)[i] = o;
    } else if (b < CONV_BLOCKS + 128) {
        int id = (b - CONV_BLOCKS) * 256 + t;       // id = n*128 + k
        int n = id >> 7, k = id & 127;
        W1t[id] = f2bf(W1[k * 256 + n]);
    } else if (b < CONV_BLOCKS + 128 + 256) {
        int id = (b - CONV_BLOCKS - 128) * 256 + t; // id = n*256 + k
        int n = id >> 8, k = id & 255;
        W2t[id] = f2bf(W2[k * 256 + n]);
    } else {
        // S1: per-chunk coarse-bucket histogram (bucket-major out)
        __shared__ int s_is32;
        __shared__ int hist[NBUCKET];
        int c = b - PREP_W_BLOCKS;
        int is32 = detect_is32_block(ew, &s_is32, t);
        for (int k = t; k < NBUCKET; k += 256) hist[k] = 0;
        __syncthreads();
        long long e0 = (long long)c * EPC;
        for (int k = t; k < EPC; k += 256) {
            int d = edge_elem(ew, is32, (long long)N_EDGES + e0 + k);
            atomicAdd(&hist[d >> 8], 1);
        }
        __syncthreads();
        for (int k = t; k < NBUCKET; k += 256)
            chunkHist[k * NCHUNK + c] = hist[k];
    }
}

// ---------------- scan1: per-bucket-row local exclusive scan + row totals ----------------
__global__ void __launch_bounds__(256) scan1_kernel(const int* __restrict__ in,
                                                    int* __restrict__ excl, int* __restrict__ bsum) {
    __shared__ int s[256];
    int b = blockIdx.x, t = threadIdx.x, i = b * 256 + t;
    int v = in[i];
    s[t] = v;
    __syncthreads();
    for (int off = 1; off < 256; off <<= 1) {
        int y = (t >= off) ? s[t - off] : 0;
        __syncthreads();
        s[t] += y;
        __syncthreads();
    }
    excl[i] = s[t] - v;
    if (t == 255) bsum[b] = s[255];
}

// ---------------- S3: scatter edges into bucket-sorted order (bsum scan inlined) ----------------
__global__ void __launch_bounds__(256) bucket_scatter_kernel(const unsigned* __restrict__ ew,
                                                             const int* __restrict__ chunkOff,
                                                             const int* __restrict__ bsum,
                                                             unsigned* __restrict__ ebuf) {
    __shared__ int s_is32;
    __shared__ int cur[NBUCKET];
    __shared__ int sc[256];
    __shared__ int ex[NBUCKET];
    int t = threadIdx.x, b = blockIdx.x;
    int is32 = detect_is32_block(ew, &s_is32, t);
    // in-block exclusive scan of bsum[196] -> global bucket bases
    int v = (t < NBUCKET) ? bsum[t] : 0;
    sc[t] = v;
    __syncthreads();
    for (int off = 1; off < 256; off <<= 1) {
        int y = (t >= off) ? sc[t - off] : 0;
        __syncthreads();
        sc[t] += y;
        __syncthreads();
    }
    if (t < NBUCKET) ex[t] = sc[t] - v;
    __syncthreads();
    for (int k = t; k < NBUCKET; k += 256) cur[k] = ex[k] + chunkOff[k * NCHUNK + b];
    __syncthreads();
    long long e0 = (long long)b * EPC;
    for (int k = t; k < EPC; k += 256) {
        long long e = e0 + k;
        unsigned s = (unsigned)edge_elem(ew, is32, e);
        int d = edge_elem(ew, is32, (long long)N_EDGES + e);
        int pos = atomicAdd(&cur[d >> 8], 1);
        ebuf[pos] = s | ((unsigned)d << 16);
    }
}

// ---------------- S4: exact per-dst sort within bucket + row_ptr + degree hist ----------------
__global__ void __launch_bounds__(256) bucket_sort_kernel(const unsigned* __restrict__ ebuf,
                                                          const int* __restrict__ bsum,
                                                          unsigned* __restrict__ edge_csr,
                                                          int* __restrict__ row_ptr,
                                                          int* __restrict__ dhist) {
    __shared__ int cnt[256];
    __shared__ int s[256];
    __shared__ int dh[64];
    __shared__ int sstart, send;
    int b = blockIdx.x, t = threadIdx.x;
    // in-block exclusive scan of bsum -> start/end of this bucket
    int v = (t < NBUCKET) ? bsum[t] : 0;
    s[t] = v;
    __syncthreads();
    for (int off = 1; off < 256; off <<= 1) {
        int y = (t >= off) ? s[t - off] : 0;
        __syncthreads();
        s[t] += y;
        __syncthreads();
    }
    if (t == b) sstart = s[t] - v;
    if (b + 1 < NBUCKET) {
        if (t == b + 1) send = s[t] - v;
    } else {
        if (t == 0) send = N_EDGES;
    }
    __syncthreads();
    int start = sstart, end = send;
    cnt[t] = 0;
    if (t < 64) dh[t] = 0;
    __syncthreads();
    for (int e = start + t; e < end; e += 256) {
        int d = (int)(ebuf[e] >> 16);
        atomicAdd(&cnt[d & 255], 1);
    }
    __syncthreads();
    int node = b * 256 + t;
    int mydeg = cnt[t];
    if (node < N_NODES) atomicAdd(&dh[mydeg < 63 ? mydeg : 63], 1);
    s[t] = mydeg;
    __syncthreads();
    for (int off = 1; off < 256; off <<= 1) {
        int y = (t >= off) ? s[t - off] : 0;
        __syncthreads();
        s[t] += y;
        __syncthreads();
    }
    int excl = s[t] - mydeg;
    if (node <= N_NODES) row_ptr[node] = start + excl;  // node==N_NODES at b=195,t=80
    cnt[t] = start + excl;  // becomes cursor
    __syncthreads();
    for (int e = start + t; e < end; e += 256) {
        unsigned pk = ebuf[e];
        int pos = atomicAdd(&cnt[(pk >> 16) & 255], 1);
        edge_csr[pos] = pk;
    }
    if (t < 64 && dh[t]) atomicAdd(&dhist[t], dh[t]);
}

// ---------------- scatter node ids into degree-grouped perm (inlined bin scan) ----------------
__global__ void __launch_bounds__(256) dscatter_kernel(const int* __restrict__ row_ptr,
                                                       const int* __restrict__ dhist,
                                                       int* __restrict__ dcur,
                                                       int* __restrict__ perm) {
    __shared__ int lh[64], lbase[64], sbase[64];
    int t = threadIdx.x, i = blockIdx.x * 256 + t;
    if (t < 64) {
        int v = dhist[t];
        int sum = v;
#pragma unroll
        for (int off = 1; off < 64; off <<= 1) {
            int y = __shfl_up(sum, off, 64);
            if (t >= off) sum += y;
        }
        sbase[t] = sum - v;
        lh[t] = 0;
    }
    __syncthreads();
    int deg = 0;
    if (i < N_NODES) {
        deg = row_ptr[i + 1] - row_ptr[i];
        if (deg > 63) deg = 63;
        atomicAdd(&lh[deg], 1);
    }
    __syncthreads();
    if (t < 64) {
        lbase[t] = lh[t] ? (sbase[t] + atomicAdd(&dcur[t], lh[t])) : 0;
        lh[t] = 0;
    }
    __syncthreads();
    if (i < N_NODES) {
        int rank = atomicAdd(&lh[deg], 1);
        perm[lbase[deg] + rank] = i;
    }
}

// ---------------- MFMA bf16 GEMM + fused alpha logits ----------------
// C[M,256] = A[M,K](bf16) @ Wt^T, stored as fp8 e4m3 (1B/ch).
// colblock == head; epilogue computes alpha_s/alpha_d from fp32 accs.
template <int K>
__global__ void __launch_bounds__(256) mfma_gemm_kernel(const ushort_t* __restrict__ A,
                                                        const ushort_t* __restrict__ Wt,
                                                        void* __restrict__ Cv, int M,
                                                        const float* __restrict__ a_src,
                                                        const float* __restrict__ a_dst,
                                                        float* __restrict__ alpha_s,
                                                        float* __restrict__ alpha_d) {
    constexpr int CPR = K / 8;
    constexpr int NT = K / 64;
    __shared__ ushort_t Bs[64 * K];
    __shared__ ushort_t As[2][64 * 64];
    __shared__ float ps[64][2], pd[64][2];

    int tid = threadIdx.x;
    int wave = tid >> 6, lane = tid & 63;
    int l15 = lane & 15, l4 = lane >> 4;
    int wr = wave >> 1, wc = wave & 1;
    int colblock = blockIdx.x;   // head
    int rowblock = blockIdx.y;

    for (int base = 0; base < 64 * CPR; base += 256) {
        int p = base + wave * 64 + lane;
        int row = p / CPR;
        int cs = p % CPR;
        int c = cs ^ (row & 7);
        const ushort_t* src = Wt + (long long)(colblock * 64 + row) * K + c * 8;
        void* dst = ((char*)Bs) + (base + wave * 64) * 16;
        gload16(src, dst);
    }
    {
        int r = lane >> 3, cs = lane & 7;
        int c = cs ^ r;
#pragma unroll
        for (int q = 0; q < 2; ++q) {
            int lrow = wave * 16 + q * 8;
            int grow = rowblock * 64 + lrow + r;
            if (grow >= M) grow = M - 1;
            const ushort_t* src = A + (long long)grow * K + c * 8;
            void* dst = ((char*)&As[0][0]) + lrow * 128;
            gload16(src, dst);
        }
    }
    __syncthreads();

    f32x4 acc[2][2] = {};
#pragma unroll
    for (int t = 0; t < NT; ++t) {
        if (t + 1 < NT) {
            int r = lane >> 3, cs = lane & 7;
            int c = cs ^ r;
#pragma unroll
            for (int q = 0; q < 2; ++q) {
                int lrow = wave * 16 + q * 8;
                int grow = rowblock * 64 + lrow + r;
                if (grow >= M) grow = M - 1;
                const ushort_t* src = A + (long long)grow * K + (t + 1) * 64 + c * 8;
                void* dst = ((char*)&As[(t + 1) & 1][0]) + lrow * 128;
                gload16(src, dst);
            }
        }
        const ushort_t* At = &As[t & 1][0];
#pragma unroll
        for (int w = 0; w < 2; ++w) {
            bf16x8 a[2], b[2];
#pragma unroll
            for (int mi = 0; mi < 2; ++mi) {
                int row = wr * 32 + mi * 16 + l15;
                int slot = (w * 4 + l4) ^ (l15 & 7);
                a[mi] = *(const bf16x8*)&At[row * 64 + slot * 8];
            }
#pragma unroll
            for (int ni = 0; ni < 2; ++ni) {
                int brow = wc * 32 + ni * 16 + l15;
                int slot = (t * 8 + w * 4 + l4) ^ (l15 & 7);
                b[ni] = *(const bf16x8*)&Bs[brow * CPR * 8 + slot * 8];
            }
#pragma unroll
            for (int mi = 0; mi < 2; ++mi)
#pragma unroll
                for (int ni = 0; ni < 2; ++ni)
                    acc[mi][ni] = __builtin_amdgcn_mfma_f32_16x16x32_bf16(a[mi], b[ni],
                                                                          acc[mi][ni], 0, 0, 0);
        }
        __syncthreads();
    }

    // ---- fused alpha partials: per-row dot with a_src/a_dst (this head) ----
    {
        float as0 = a_src[colblock * 64 + wc * 32 + l15];
        float as1 = a_src[colblock * 64 + wc * 32 + 16 + l15];
        float ad0 = a_dst[colblock * 64 + wc * 32 + l15];
        float ad1 = a_dst[colblock * 64 + wc * 32 + 16 + l15];
#pragma unroll
        for (int mi = 0; mi < 2; ++mi)
#pragma unroll
            for (int q = 0; q < 4; ++q) {
                float sv = acc[mi][0][q] * as0 + acc[mi][1][q] * as1;
                float dv = acc[mi][0][q] * ad0 + acc[mi][1][q] * ad1;
#pragma unroll
                for (int w = 1; w < 16; w <<= 1) {
                    sv += __shfl_xor(sv, w, 64);
                    dv += __shfl_xor(dv, w, 64);
                }
                if (l15 == 0) {
                    int row = wr * 32 + mi * 16 + l4 * 4 + q;
                    ps[row][wc] = sv;
                    pd[row][wc] = dv;
                }
            }
    }

    // ---- epilogue: repack via LDS (bf16 staging), store fp8 ----
    ushort_t* ep = ((ushort_t*)&As[0][0]) + wave * 1280;
#pragma unroll
    for (int mi = 0; mi < 2; ++mi)
#pragma unroll
        for (int ni = 0; ni < 2; ++ni)
#pragma unroll
            for (int q = 0; q < 4; ++q) {
                int row = mi * 16 + l4 * 4 + q;
                int col = ni * 16 + l15;
                ep[row * 40 + col] = f2bf(acc[mi][ni][q]);
            }
    __syncthreads();
#pragma unroll
    for (int j = 0; j < 2; ++j) {
        int p = lane * 2 + j;
        int row = p >> 2, seg = p & 3;
        uint4 v = *(const uint4*)&ep[row * 40 + seg * 8];
        int grow = rowblock * 64 + wr * 32 + row;
        int gcol = colblock * 64 + wc * 32 + seg * 8;
        if (grow < M) {
            f32x2 f01 = bfpair(v.x), f23 = bfpair(v.y);
            f32x2 f45 = bfpair(v.z), f67 = bfpair(v.w);
            int d0 = 0, d1 = 0;
            d0 = __builtin_amdgcn_cvt_pk_fp8_f32(f01.x, f01.y, d0, false);
            d0 = __builtin_amdgcn_cvt_pk_fp8_f32(f23.x, f23.y, d0, true);
            d1 = __builtin_amdgcn_cvt_pk_fp8_f32(f45.x, f45.y, d1, false);
            d1 = __builtin_amdgcn_cvt_pk_fp8_f32(f67.x, f67.y, d1, true);
            uint2 o; o.x = (unsigned)d0; o.y = (unsigned)d1;
            *(uint2*)((char*)Cv + (long long)grow * 256 + gcol) = o;
        }
    }
    if (tid < 64) {
        int ga = rowblock * 64 + tid;
        if (ga < M) {
            alpha_s[ga * 4 + colblock] = ps[tid][0] + ps[tid][1];
            alpha_d[ga * 4 + colblock] = pd[tid][0] + pd[tid][1];
        }
    }
}

// ---------------- softmax-weighted aggregation (one wave per node, degree-grouped) ----------------
// Per-edge weight exp deduplicated across the 16-lane head group:
// lane l computes wt for edge (l15 & (U-1)), head (l>>4); redistribution via __shfl.
template <int U>
__device__ __forceinline__ void agg_batch(int p, const unsigned* __restrict__ edge_csr,
                                          const float* __restrict__ alpha_s,
                                          const char* __restrict__ gb, unsigned loff,
                                          int l15, int hd, float ad, float& wsum,
                                          f32x2& acc01, f32x2& acc23) {
    int j[U]; unsigned hh[U];
#pragma unroll
    for (int u = 0; u < U; ++u) j[u] = (int)(edge_csr[p + u] & 0xFFFFu);
#pragma unroll
    for (int u = 0; u < U; ++u)
        hh[u] = *(const unsigned*)(gb + (((unsigned)j[u] << 8) | loff));
    // one exp per lane (direct load avoids runtime-indexed register array -> scratch)
    int myj = (int)(edge_csr[p + (l15 & (U - 1))] & 0xFFFFu);
    float e = alpha_s[myj * 4 + hd] + ad;
    e = e > 0.f ? e : 0.2f * e;
    float wt_mine = __expf(e);
    int sbase = hd << 4;
#pragma unroll
    for (int u = 0; u < U; ++u) {
        float wt = __shfl(wt_mine, sbase | u, 64);
        wsum += wt;
        f32x2 wp; wp.x = wt; wp.y = wt;
        pkfma(acc01, wp, __builtin_amdgcn_cvt_pk_f32_fp8(hh[u], false));
        pkfma(acc23, wp, __builtin_amdgcn_cvt_pk_f32_fp8(hh[u], true));
    }
}

template <int LAYER>
__global__ void __launch_bounds__(256) aggregate_kernel(
    const void* __restrict__ gv, const float* __restrict__ alpha_s,
    const float* __restrict__ alpha_d, const int* __restrict__ row_ptr,
    const unsigned* __restrict__ edge_csr, const int* __restrict__ perm,
    const float* __restrict__ bias, ushort_t* __restrict__ out_bf,
    const float* __restrict__ fc_w, const float* __restrict__ fc_b,
    float* __restrict__ final_out) {
    int wave = threadIdx.x >> 6;
    int lane = threadIdx.x & 63;
    // LPT scheduling: perm is ascending-by-degree; index in reverse so the
    // heaviest blocks dispatch first and light blocks backfill the tail.
    int slot = N_NODES - 1 - (blockIdx.x * 4 + wave);
    int i = __builtin_amdgcn_readfirstlane(perm[slot]);
    int hd = lane >> 4;
    int l15 = lane & 15;
    const char* gb = (const char*)gv;           // fp8 rows: 256 B/row
    unsigned loff = (unsigned)(lane << 2);

    float ad = alpha_d[i * 4 + hd];
    // self loop
    float e0 = alpha_s[i * 4 + hd] + ad;
    e0 = e0 > 0.f ? e0 : 0.2f * e0;
    float w0 = __expf(e0);
    f32x2 acc01 = {0.f, 0.f}, acc23 = {0.f, 0.f};
    {
        unsigned sv = *(const unsigned*)(gb + (((unsigned)i << 8) | loff));
        f32x2 wp0; wp0.x = w0; wp0.y = w0;
        pkfma(acc01, wp0, __builtin_amdgcn_cvt_pk_f32_fp8(sv, false));
        pkfma(acc23, wp0, __builtin_amdgcn_cvt_pk_f32_fp8(sv, true));
    }
    float wsum = w0;

    int p = __builtin_amdgcn_readfirstlane(row_ptr[i]);
    int p1 = __builtin_amdgcn_readfirstlane(row_ptr[i + 1]);
    for (; p + 16 <= p1; p += 16)
        agg_batch<16>(p, edge_csr, alpha_s, gb, loff, l15, hd, ad, wsum, acc01, acc23);
    for (; p + 8 <= p1; p += 8)
        agg_batch<8>(p, edge_csr, alpha_s, gb, loff, l15, hd, ad, wsum, acc01, acc23);
    for (; p + 4 <= p1; p += 4)
        agg_batch<4>(p, edge_csr, alpha_s, gb, loff, l15, hd, ad, wsum, acc01, acc23);
    for (; p < p1; ++p)
        agg_batch<1>(p, edge_csr, alpha_s, gb, loff, l15, hd, ad, wsum, acc01, acc23);

    float inv = 1.f / (wsum + 1e-16f);
    int c = lane * 4;
    float4 b4 = *(const float4*)&bias[c];
    float o0 = acc01.x * inv + b4.x;
    float o1 = acc01.y * inv + b4.y;
    float o2 = acc23.x * inv + b4.z;
    float o3 = acc23.y * inv + b4.w;
    o0 = o0 > 0.f ? o0 : __expf(o0) - 1.f;
    o1 = o1 > 0.f ? o1 : __expf(o1) - 1.f;
    o2 = o2 > 0.f ? o2 : __expf(o2) - 1.f;
    o3 = o3 > 0.f ? o3 : __expf(o3) - 1.f;
    if (LAYER == 1) {
        ushort4 o;
        o.x = f2bf(o0); o.y = f2bf(o1); o.z = f2bf(o2); o.w = f2bf(o3);
        ((ushort4*)out_bf)[(long long)i * 64 + lane] = o;
    } else {
        float4 fw = *(const float4*)&fc_w[c];
        float dot = o0 * fw.x + o1 * fw.y + o2 * fw.z + o3 * fw.w;
#pragma unroll
        for (int off = 32; off; off >>= 1) dot += __shfl_down(dot, off, 64);
        if (lane == 0) final_out[i] = 1.f / (1.f + __expf(-(dot + fc_b[0])));
    }
}

// ---------------- launch ----------------
extern "C" void kernel_launch(void* const* d_in, const int* in_sizes, int n_in,
                              void* d_out, int out_size, void* d_ws, size_t ws_size,
                              hipStream_t stream) {
    const float* x   = (const float*)d_in[0];
    const unsigned* ei = (const unsigned*)d_in[1];
    const float* W1  = (const float*)d_in[2];
    const float* as1 = (const float*)d_in[3];
    const float* ad1 = (const float*)d_in[4];
    const float* b1  = (const float*)d_in[5];
    const float* W2  = (const float*)d_in[6];
    const float* as2 = (const float*)d_in[7];
    const float* ad2 = (const float*)d_in[8];
    const float* b2  = (const float*)d_in[9];
    const float* fcw = (const float*)d_in[10];
    const float* fcb = (const float*)d_in[11];

    char* ws = (char*)d_ws;
    void* g1f8         = (void*)(ws + 0);               // 12.8 MB (fp8)
    void* g2f8         = (void*)(ws + 12800000);        // 12.8 MB (fp8)
    ushort_t* hactbf   = (ushort_t*)(ws + 25600000);    // 25.6 MB
    ushort_t* xbf      = (ushort_t*)(ws + 51200000);    // 12.8 MB
    ushort_t* W1t      = (ushort_t*)(ws + 64000000);
    ushort_t* W2t      = (ushort_t*)(ws + 64100000);
    float* asv         = (float*)(ws + 64300000);
    float* adv         = (float*)(ws + 65100000);
    int* row_ptr       = (int*)(ws + 65900000);         // 50001 ints
    int* chunkHist     = (int*)(ws + 66110000);         // 50176 ints
    int* chunkOff      = (int*)(ws + 66320000);         // 50176 ints (row-local prefixes)
    unsigned* ebuf     = (unsigned*)(ws + 66530000);    // 3.2 MB (bucket-sorted)
    unsigned* edge_csr = (unsigned*)(ws + 69730000);    // 3.2 MB (exact CSR)
    int* perm          = (int*)(ws + 72930000);         // 200 KB (degree-grouped order)
    int* bsum          = (int*)(ws + 73130000);         // 196 ints
    int* dhist         = (int*)(ws + 73132048);         // 64 ints
    int* dcur          = (int*)(ws + 73132304);         // 64 ints

    prep_kernel<<<PREP_W_BLOCKS + NCHUNK, 256, 0, stream>>>(x, xbf, W1, W1t, W2, W2t,
                                                            ei, chunkHist, dhist, dcur);
    scan1_kernel<<<SCAN_BLOCKS, 256, 0, stream>>>(chunkHist, chunkOff, bsum);
    bucket_scatter_kernel<<<NCHUNK, 256, 0, stream>>>(ei, chunkOff, bsum, ebuf);
    bucket_sort_kernel<<<NBUCKET, 256, 0, stream>>>(ebuf, bsum, edge_csr, row_ptr, dhist);
    dscatter_kernel<<<SCAN_BLOCKS, 256, 0, stream>>>(row_ptr, dhist, dcur, perm);

    // layer 1 (g stored fp8)
    mfma_gemm_kernel<128><<<dim3(4, (N_NODES + 63) / 64), 256, 0, stream>>>(
        xbf, W1t, g1f8, N_NODES, as1, ad1, asv, adv);
    aggregate_kernel<1><<<N_NODES / 4, 256, 0, stream>>>(g1f8, asv, adv, row_ptr, edge_csr, perm,
                                                         b1, hactbf, nullptr, nullptr, nullptr);
    // layer 2 (g stored fp8)
    mfma_gemm_kernel<256><<<dim3(4, (N_NODES + 63) / 64), 256, 0, stream>>>(
        hactbf, W2t, g2f8, N_NODES, as2, ad2, asv, adv);
    aggregate_kernel<2><<<N_NODES / 4, 256, 0, stream>>>(g2f8, asv, adv, row_ptr, edge_csr, perm,
                                                         b2, nullptr, fcw, fcb, (float*)d_out);
}